// Round 1
// baseline (1472.684 us; speedup 1.0000x reference)
//
#include <hip/hip_runtime.h>
#include <math.h>

#define Nn 1024
#define Hh 2048
#define Ee 64
#define Ii 512
#define SIi 512
#define TOPK 8
#define MAXS 12288   // 8192 pairs + 64 experts * 63 padding max, rounded up

#define BM 64
#define BN 64
#define BK 32
#define LDP 40   // padded LDS leading dim (bf16 elems): 80B rows -> conflict-light

typedef __attribute__((ext_vector_type(8))) short s16x8;
typedef __attribute__((ext_vector_type(4))) float f32x4;

__device__ inline short f2bf(float f) {
    unsigned u = __float_as_uint(f);
    unsigned r = (u + 0x7FFFu + ((u >> 16) & 1u)) >> 16;  // RNE
    return (short)r;
}

__device__ inline float silu(float x) { return x / (1.f + expf(-x)); }

// ---------------- gating: logits (fp32), top-8, softmax, shared sigmoid gate ----
__global__ __launch_bounds__(256) void k_gate(
    const float* __restrict__ h, const float* __restrict__ gate_w,
    const float* __restrict__ sh_gate1_w,
    int* __restrict__ topi, float* __restrict__ rw,
    int* __restrict__ counts, float* __restrict__ shg)
{
    __shared__ float xs[Hh];
    __shared__ float part[256];
    __shared__ float logits[Ee];
    int n = blockIdx.x;
    const float* x = h + (long)n * Hh;
    for (int i = threadIdx.x; i < Hh / 4; i += 256)
        ((float4*)xs)[i] = ((const float4*)x)[i];
    __syncthreads();

    // logits: thread = (e, quarter)
    {
        int e = threadIdx.x & 63, q = threadIdx.x >> 6;
        const float* w = gate_w + (long)e * Hh + q * 512;
        const float* xq = xs + q * 512;
        float s = 0.f;
        for (int k = 0; k < 512; ++k) s += xq[k] * w[k];
        part[threadIdx.x] = s;
    }
    __syncthreads();
    if (threadIdx.x < 64)
        logits[threadIdx.x] = part[threadIdx.x] + part[threadIdx.x + 64]
                            + part[threadIdx.x + 128] + part[threadIdx.x + 192];
    __syncthreads();

    // shared gate scalar: sigmoid(x . sh_gate1_w)
    {
        float s = 0.f;
        for (int k = threadIdx.x; k < Hh; k += 256) s += xs[k] * sh_gate1_w[k];
        part[threadIdx.x] = s;
    }
    __syncthreads();
    for (int off = 128; off > 0; off >>= 1) {
        if (threadIdx.x < off) part[threadIdx.x] += part[threadIdx.x + off];
        __syncthreads();
    }

    if (threadIdx.x == 0) {
        shg[n] = 1.f / (1.f + expf(-part[0]));
        float v[TOPK]; int ix[TOPK];
        for (int kk = 0; kk < TOPK; ++kk) {
            float best = -1e30f; int bi = 0;
            for (int e = 0; e < Ee; ++e)
                if (logits[e] > best) { best = logits[e]; bi = e; }
            v[kk] = best; ix[kk] = bi; logits[bi] = -1e30f;
        }
        float mx = v[0], den = 0.f, w8[TOPK];
        for (int kk = 0; kk < TOPK; ++kk) { w8[kk] = expf(v[kk] - mx); den += w8[kk]; }
        for (int kk = 0; kk < TOPK; ++kk) {
            topi[n * TOPK + kk] = ix[kk];
            rw[n * TOPK + kk] = w8[kk] / den;
            atomicAdd(&counts[ix[kk]], 1);
        }
    }
}

// ---------------- padded prefix offsets + cursor init ----------------
__global__ void k_offsets(const int* __restrict__ counts,
                          int* __restrict__ padoff, int* __restrict__ cursor)
{
    if (threadIdx.x == 0) {
        int acc = 0;
        for (int e = 0; e < Ee; ++e) {
            padoff[e] = acc;
            acc += (counts[e] + BM - 1) & ~(BM - 1);
        }
        padoff[Ee] = acc;
    }
    if (threadIdx.x < Ee) cursor[threadIdx.x] = 0;
}

// ---------------- scatter pairs to per-expert slot lists ----------------
__global__ __launch_bounds__(256) void k_scatter(
    const int* __restrict__ topi, const float* __restrict__ rw,
    const int* __restrict__ padoff, int* __restrict__ cursor,
    int* __restrict__ rows, float* __restrict__ wt)
{
    int p = blockIdx.x * 256 + threadIdx.x;  // 0..8191
    int n = p >> 3;
    int e = topi[p];
    int pos = atomicAdd(&cursor[e], 1);
    int slot = padoff[e] + pos;
    rows[slot] = n;
    wt[slot] = rw[p];
}

// ---------------- NT GEMM, fp32 in -> bf16 MFMA -> fp32 out ----------------
// MODE 0: routed gu.   A=h gathered via rows[], C store to gu_buf (slot-major)
// MODE 1: routed down. A=inter (slot-major direct), epilogue atomicAdd scatter to out
// MODE 2: shared g/u.  A=h direct, C store
// MODE 3: shared down. A=sh_inter direct, C store = scale[row] * v
template<int MODE>
__global__ __launch_bounds__(256) void gemm_nt(
    const float* __restrict__ A, int lda,
    const float* __restrict__ Bbase, long strideB, int ldb,
    float* __restrict__ Cout, int ldc,
    const int* __restrict__ counts, int fixedM,
    const int* __restrict__ padoff,
    const int* __restrict__ rows,
    const float* __restrict__ scale,
    int K, int ntiles)
{
    int e = blockIdx.x / ntiles;
    int ntile = blockIdx.x % ntiles;
    int Me = counts ? counts[e] : fixedM;
    int mtile = blockIdx.y;
    if (mtile * BM >= Me) return;
    int m0 = (padoff ? padoff[e] : 0) + mtile * BM;
    const float* Bp = Bbase + (long)e * strideB;

    __shared__ short As[BM * LDP];
    __shared__ short Bs[BN * LDP];
    __shared__ int arow[BM];

    if (threadIdx.x < BM) {
        int r;
        if (MODE == 0) r = rows[m0 + threadIdx.x];
        else           r = m0 + threadIdx.x;
        arow[threadIdx.x] = r;
    }
    __syncthreads();

    f32x4 acc[4];
    #pragma unroll
    for (int c = 0; c < 4; ++c) acc[c] = (f32x4){0.f, 0.f, 0.f, 0.f};

    int lane = threadIdx.x & 63;
    int wave = threadIdx.x >> 6;
    int fr   = lane & 15;
    int quad = lane >> 4;
    int n0 = ntile * BN;

    for (int k0 = 0; k0 < K; k0 += BK) {
        float4 av[2], bv[2];
        #pragma unroll
        for (int it = 0; it < 2; ++it) {
            int idx = threadIdx.x + it * 256;   // 0..511 over 64 rows x 8 float4
            int m = idx >> 3, kq = idx & 7;
            int r = arow[m];
            if (MODE == 0 && r < 0) av[it] = make_float4(0.f, 0.f, 0.f, 0.f);
            else av[it] = *((const float4*)(A + (long)r * lda + k0 + kq * 4));
            int nn = n0 + m;
            bv[it] = *((const float4*)(Bp + (long)nn * ldb + k0 + kq * 4));
        }
        __syncthreads();   // previous iteration's LDS reads complete
        #pragma unroll
        for (int it = 0; it < 2; ++it) {
            int idx = threadIdx.x + it * 256;
            int m = idx >> 3, kq = idx & 7;
            short4 pa, pb;
            pa.x = f2bf(av[it].x); pa.y = f2bf(av[it].y);
            pa.z = f2bf(av[it].z); pa.w = f2bf(av[it].w);
            pb.x = f2bf(bv[it].x); pb.y = f2bf(bv[it].y);
            pb.z = f2bf(bv[it].z); pb.w = f2bf(bv[it].w);
            *(short4*)(&As[m * LDP + kq * 4]) = pa;
            *(short4*)(&Bs[m * LDP + kq * 4]) = pb;
        }
        __syncthreads();   // LDS tiles visible

        // a_frag: A[m = wave*16 + (lane&15)][k = quad*8 + j]
        s16x8 af = *(const s16x8*)(&As[(wave * 16 + fr) * LDP + quad * 8]);
        #pragma unroll
        for (int c = 0; c < 4; ++c) {
            s16x8 bf = *(const s16x8*)(&Bs[(c * 16 + fr) * LDP + quad * 8]);
            acc[c] = __builtin_amdgcn_mfma_f32_16x16x32_bf16(af, bf, acc[c], 0, 0, 0);
        }
    }

    // epilogue: C/D layout col = lane&15, row = quad*4 + reg
    #pragma unroll
    for (int c = 0; c < 4; ++c) {
        int col = n0 + c * 16 + fr;
        #pragma unroll
        for (int r2 = 0; r2 < 4; ++r2) {
            int mrow = m0 + wave * 16 + quad * 4 + r2;
            float v = acc[c][r2];
            if (MODE == 0) {
                Cout[(long)mrow * ldc + col] = v;           // slot-major gu
            } else if (MODE == 1) {
                int t = rows[mrow];
                if (t >= 0) atomicAdd(&Cout[(long)t * ldc + col], v);
            } else if (MODE == 2) {
                Cout[(long)mrow * ldc + col] = v;
            } else {
                Cout[(long)mrow * ldc + col] = scale[mrow] * v;
            }
        }
    }
}

// ---------------- routed inter = silu(g)*u * routing_weight ----------------
__global__ __launch_bounds__(256) void k_inter(
    const float* __restrict__ gu, const int* __restrict__ rows,
    const float* __restrict__ wt, float* __restrict__ inter)
{
    int i = blockIdx.x * 256 + threadIdx.x;   // over MAXS*512
    int slot = i >> 9, ii = i & 511;
    float v = 0.f;
    if (rows[slot] >= 0) {
        float g = gu[(long)slot * 1024 + ii];
        float u = gu[(long)slot * 1024 + 512 + ii];
        v = silu(g) * u * wt[slot];
    }
    inter[(long)slot * 512 + ii] = v;
}

// ---------------- shared inter = silu(g)*u ----------------
__global__ __launch_bounds__(256) void k_sh_inter(
    const float* __restrict__ g, const float* __restrict__ u, float* __restrict__ si)
{
    int i = blockIdx.x * 256 + threadIdx.x;   // 1024*512
    float gv = g[i];
    si[i] = silu(gv) * u[i];
}

extern "C" void kernel_launch(void* const* d_in, const int* in_sizes, int n_in,
                              void* d_out, int out_size, void* d_ws, size_t ws_size,
                              hipStream_t stream) {
    const float* h          = (const float*)d_in[0];
    const float* gate_w     = (const float*)d_in[1];
    const float* gu_w       = (const float*)d_in[2];
    const float* dp_w       = (const float*)d_in[3];
    const float* sh_gate_w  = (const float*)d_in[4];
    const float* sh_up_w    = (const float*)d_in[5];
    const float* sh_down_w  = (const float*)d_in[6];
    const float* sh_gate1_w = (const float*)d_in[7];
    float* out = (float*)d_out;

    char* ws = (char*)d_ws;
    size_t off = 0;
    auto alloc = [&](size_t bytes) {
        void* p = ws + off; off += (bytes + 255) & ~(size_t)255; return p;
    };
    int*   topi    = (int*)  alloc(Nn * TOPK * 4);
    float* rw      = (float*)alloc(Nn * TOPK * 4);
    int*   counts  = (int*)  alloc(Ee * 4);
    int*   padoff  = (int*)  alloc((Ee + 1) * 4);
    int*   cursor  = (int*)  alloc(Ee * 4);
    float* shg     = (float*)alloc(Nn * 4);
    int*   rows    = (int*)  alloc(MAXS * 4);
    float* wt      = (float*)alloc(MAXS * 4);
    float* gu_buf  = (float*)alloc((size_t)MAXS * 1024 * 4);
    float* interb  = (float*)alloc((size_t)MAXS * 512 * 4);
    float* gbuf    = (float*)alloc((size_t)Nn * SIi * 4);
    float* ubuf    = (float*)alloc((size_t)Nn * SIi * 4);
    float* shint   = (float*)alloc((size_t)Nn * SIi * 4);

    hipMemsetAsync(counts, 0, Ee * 4, stream);
    hipMemsetAsync(rows, 0xFF, MAXS * 4, stream);   // -1 sentinel
    hipMemsetAsync(wt, 0, MAXS * 4, stream);

    k_gate<<<Nn, 256, 0, stream>>>(h, gate_w, sh_gate1_w, topi, rw, counts, shg);
    k_offsets<<<1, 64, 0, stream>>>(counts, padoff, cursor);
    k_scatter<<<Nn * TOPK / 256, 256, 0, stream>>>(topi, rw, padoff, cursor, rows, wt);

    // routed up/gate: C (slots x 1024) = gathered_X @ gu_w[e]^T
    gemm_nt<0><<<dim3(Ee * 16, 16), 256, 0, stream>>>(
        h, Hh, gu_w, (long)1024 * Hh, Hh, gu_buf, 1024,
        counts, 0, padoff, rows, nullptr, Hh, 16);

    k_inter<<<MAXS * 2, 256, 0, stream>>>(gu_buf, rows, wt, interb);

    // shared gate / up: (1024 x 512) = X @ W^T
    gemm_nt<2><<<dim3(8, 16), 256, 0, stream>>>(
        h, Hh, sh_gate_w, 0, Hh, gbuf, SIi,
        nullptr, Nn, nullptr, nullptr, nullptr, Hh, 8);
    gemm_nt<2><<<dim3(8, 16), 256, 0, stream>>>(
        h, Hh, sh_up_w, 0, Hh, ubuf, SIi,
        nullptr, Nn, nullptr, nullptr, nullptr, Hh, 8);

    k_sh_inter<<<Nn * SIi / 256, 256, 0, stream>>>(gbuf, ubuf, shint);

    // shared down: out = shg[n] * (sh_inter @ sh_down_w^T)   (plain store, runs first)
    gemm_nt<3><<<dim3(32, 16), 256, 0, stream>>>(
        shint, SIi, sh_down_w, 0, SIi, out, Hh,
        nullptr, Nn, nullptr, nullptr, shg, SIi, 32);

    // routed down: out += inter @ dp_w[e]^T  (atomic scatter-add)
    gemm_nt<1><<<dim3(Ee * 32, 16), 256, 0, stream>>>(
        interb, Ii, dp_w, (long)Hh * Ii, Ii, out, Hh,
        counts, 0, padoff, rows, nullptr, Ii, 32);
}

// Round 2
// 1345.801 us; speedup vs baseline: 1.0943x; 1.0943x over previous
//
#include <hip/hip_runtime.h>
#include <hip/hip_bf16.h>
#include <math.h>

#define Nn 1024
#define Hh 2048
#define Ee 64
#define Ii 512
#define SIi 512
#define TOPK 8
#define MAXS 12288   // 8192 pairs + 64 experts * 63 padding max, rounded up

#define BM 64
#define BN 256
#define BK 32
#define LDP 40   // padded LDS leading dim (bf16 elems): 80B rows -> 2-way max (free)

typedef __attribute__((ext_vector_type(8))) short s16x8;
typedef __attribute__((ext_vector_type(4))) float f32x4;

// fp32x4 -> packed bf16x4 (RNE) via v_cvt_pk_bf16_f32
__device__ inline int2 cvt4(float4 v) {
    union { __hip_bfloat162 h; int i; } a, b;
    a.h = __float22bfloat162_rn(make_float2(v.x, v.y));
    b.h = __float22bfloat162_rn(make_float2(v.z, v.w));
    int2 r; r.x = a.i; r.y = b.i; return r;
}

__device__ inline float silu(float x) { return x / (1.f + expf(-x)); }

// ---------------- gating: logits (fp32), top-8, softmax, shared sigmoid gate ----
__global__ __launch_bounds__(256) void k_gate(
    const float* __restrict__ h, const float* __restrict__ gate_w,
    const float* __restrict__ sh_gate1_w,
    int* __restrict__ topi, float* __restrict__ rw,
    int* __restrict__ counts, float* __restrict__ shg)
{
    __shared__ float xs[Hh];
    __shared__ float part[256];
    __shared__ float logits[Ee];
    int n = blockIdx.x;
    const float* x = h + (long)n * Hh;
    for (int i = threadIdx.x; i < Hh / 4; i += 256)
        ((float4*)xs)[i] = ((const float4*)x)[i];
    __syncthreads();

    // logits: thread = (e, quarter), float4 inner loop
    {
        int e = threadIdx.x & 63, q = threadIdx.x >> 6;
        const float4* w = (const float4*)(gate_w + (long)e * Hh + q * 512);
        const float4* xq = (const float4*)(xs + q * 512);
        float s = 0.f;
        for (int k = 0; k < 128; ++k) {
            float4 a = xq[k], b = w[k];
            s += a.x * b.x + a.y * b.y + a.z * b.z + a.w * b.w;
        }
        part[threadIdx.x] = s;
    }
    __syncthreads();
    if (threadIdx.x < 64)
        logits[threadIdx.x] = part[threadIdx.x] + part[threadIdx.x + 64]
                            + part[threadIdx.x + 128] + part[threadIdx.x + 192];
    __syncthreads();

    // shared gate scalar: sigmoid(x . sh_gate1_w)
    {
        float s = 0.f;
        for (int k = threadIdx.x; k < Hh; k += 256) s += xs[k] * sh_gate1_w[k];
        part[threadIdx.x] = s;
    }
    __syncthreads();
    for (int off = 128; off > 0; off >>= 1) {
        if (threadIdx.x < off) part[threadIdx.x] += part[threadIdx.x + off];
        __syncthreads();
    }

    if (threadIdx.x == 0) {
        shg[n] = 1.f / (1.f + expf(-part[0]));
        float v[TOPK]; int ix[TOPK];
        for (int kk = 0; kk < TOPK; ++kk) {
            float best = -1e30f; int bi = 0;
            for (int e = 0; e < Ee; ++e)
                if (logits[e] > best) { best = logits[e]; bi = e; }
            v[kk] = best; ix[kk] = bi; logits[bi] = -1e30f;
        }
        float mx = v[0], den = 0.f, w8[TOPK];
        for (int kk = 0; kk < TOPK; ++kk) { w8[kk] = expf(v[kk] - mx); den += w8[kk]; }
        for (int kk = 0; kk < TOPK; ++kk) {
            topi[n * TOPK + kk] = ix[kk];
            rw[n * TOPK + kk] = w8[kk] / den;
            atomicAdd(&counts[ix[kk]], 1);
        }
    }
}

// ---------------- padded prefix offsets + cursor init ----------------
__global__ void k_offsets(const int* __restrict__ counts,
                          int* __restrict__ padoff, int* __restrict__ cursor)
{
    if (threadIdx.x == 0) {
        int acc = 0;
        for (int e = 0; e < Ee; ++e) {
            padoff[e] = acc;
            acc += (counts[e] + BM - 1) & ~(BM - 1);
        }
        padoff[Ee] = acc;
    }
    if (threadIdx.x < Ee) cursor[threadIdx.x] = 0;
}

// ---------------- scatter pairs to per-expert slot lists ----------------
__global__ __launch_bounds__(256) void k_scatter(
    const int* __restrict__ topi, const float* __restrict__ rw,
    const int* __restrict__ padoff, int* __restrict__ cursor,
    int* __restrict__ rows, float* __restrict__ wt, int* __restrict__ slotof)
{
    int p = blockIdx.x * 256 + threadIdx.x;  // 0..8191
    int n = p >> 3;
    int e = topi[p];
    int pos = atomicAdd(&cursor[e], 1);
    int slot = padoff[e] + pos;
    rows[slot] = n;
    wt[slot] = rw[p];
    slotof[p] = slot;
}

// ---------------- NT GEMM, fp32 in -> bf16 MFMA -> fp32 out ----------------
// Tile: 64(M) x 256(N) x 32(K). 4 waves, each wave computes 64x64.
// Register prefetch of next K-tile issued before the MFMA block.
// MODE 0: routed gu.   A=h gathered via rows[], C store to gu_buf (slot-major)
// MODE 1: routed down. A=inter (slot-major), C store to dbuf (slot-major)
// MODE 2: shared g/u.  A=h direct, C store
// MODE 3: shared down. A=sh_inter direct, C store = scale[row] * v
template<int MODE>
__global__ __launch_bounds__(256, 3) void gemm_nt(
    const float* __restrict__ A, int lda,
    const float* __restrict__ Bbase, long strideB, int ldb,
    float* __restrict__ Cout, int ldc,
    const int* __restrict__ counts, int fixedM,
    const int* __restrict__ padoff,
    const int* __restrict__ rows,
    const float* __restrict__ scale,
    int K, int ntiles)
{
    int e = blockIdx.x / ntiles;
    int ntile = blockIdx.x % ntiles;
    int Me = counts ? counts[e] : fixedM;
    int mtile = blockIdx.y;
    if (mtile * BM >= Me) return;
    int m0 = (padoff ? padoff[e] : 0) + mtile * BM;
    const float* Bp = Bbase + (long)e * strideB;

    __shared__ short As[BM * LDP];
    __shared__ short Bs[BN * LDP];
    __shared__ int arow[BM];

    if (threadIdx.x < BM) {
        int r;
        if (MODE == 0) r = rows[m0 + threadIdx.x];
        else           r = m0 + threadIdx.x;
        arow[threadIdx.x] = r;
    }
    __syncthreads();

    f32x4 acc[4][4];
    #pragma unroll
    for (int cm = 0; cm < 4; ++cm)
        #pragma unroll
        for (int cn = 0; cn < 4; ++cn)
            acc[cm][cn] = (f32x4){0.f, 0.f, 0.f, 0.f};

    int lane = threadIdx.x & 63;
    int wave = threadIdx.x >> 6;
    int fr   = lane & 15;
    int quad = lane >> 4;
    int n0 = ntile * BN;

    float4 av[2], bv[8];

    auto issue_loads = [&](int k0) {
        #pragma unroll
        for (int it = 0; it < 2; ++it) {          // A: 64 rows x 8 float4
            int s = threadIdx.x + it * 256;
            int m = s >> 3, kq = s & 7;
            int r = arow[m];
            if (MODE == 0 && r < 0) av[it] = make_float4(0.f, 0.f, 0.f, 0.f);
            else av[it] = *((const float4*)(A + (long)r * lda + k0 + kq * 4));
        }
        #pragma unroll
        for (int it = 0; it < 8; ++it) {          // B: 256 rows x 8 float4
            int s = threadIdx.x + it * 256;
            int nn = s >> 3, kq = s & 7;
            bv[it] = *((const float4*)(Bp + (long)(n0 + nn) * ldb + k0 + kq * 4));
        }
    };

    issue_loads(0);

    for (int k0 = 0; k0 < K; k0 += BK) {
        __syncthreads();   // everyone done reading LDS from previous iter
        #pragma unroll
        for (int it = 0; it < 2; ++it) {
            int s = threadIdx.x + it * 256;
            int m = s >> 3, kq = s & 7;
            *(int2*)(&As[m * LDP + kq * 4]) = cvt4(av[it]);
        }
        #pragma unroll
        for (int it = 0; it < 8; ++it) {
            int s = threadIdx.x + it * 256;
            int nn = s >> 3, kq = s & 7;
            *(int2*)(&Bs[nn * LDP + kq * 4]) = cvt4(bv[it]);
        }
        __syncthreads();   // LDS tiles visible

        if (k0 + BK < K) issue_loads(k0 + BK);   // prefetch; waited at next store

        s16x8 af[4], bf[4];
        #pragma unroll
        for (int cm = 0; cm < 4; ++cm)
            af[cm] = *(const s16x8*)(&As[(cm * 16 + fr) * LDP + quad * 8]);
        #pragma unroll
        for (int cn = 0; cn < 4; ++cn)
            bf[cn] = *(const s16x8*)(&Bs[(wave * 64 + cn * 16 + fr) * LDP + quad * 8]);
        #pragma unroll
        for (int cm = 0; cm < 4; ++cm)
            #pragma unroll
            for (int cn = 0; cn < 4; ++cn)
                acc[cm][cn] = __builtin_amdgcn_mfma_f32_16x16x32_bf16(
                    af[cm], bf[cn], acc[cm][cn], 0, 0, 0);
    }

    // epilogue: C/D layout col = lane&15, row = quad*4 + reg
    #pragma unroll
    for (int cm = 0; cm < 4; ++cm) {
        #pragma unroll
        for (int cn = 0; cn < 4; ++cn) {
            int col = n0 + wave * 64 + cn * 16 + fr;
            #pragma unroll
            for (int r2 = 0; r2 < 4; ++r2) {
                int mrow = m0 + cm * 16 + quad * 4 + r2;
                float v = acc[cm][cn][r2];
                if (MODE == 3) Cout[(long)mrow * ldc + col] = scale[mrow] * v;
                else           Cout[(long)mrow * ldc + col] = v;
            }
        }
    }
}

// ---------------- routed inter = silu(g)*u * routing_weight ----------------
__global__ __launch_bounds__(256) void k_inter(
    const float* __restrict__ gu, const int* __restrict__ rows,
    const float* __restrict__ wt, float* __restrict__ inter)
{
    int i = blockIdx.x * 256 + threadIdx.x;   // over MAXS*512
    int slot = i >> 9, ii = i & 511;
    float v = 0.f;
    if (rows[slot] >= 0) {
        float g = gu[(long)slot * 1024 + ii];
        float u = gu[(long)slot * 1024 + 512 + ii];
        v = silu(g) * u * wt[slot];
    }
    inter[(long)slot * 512 + ii] = v;
}

// ---------------- shared inter = silu(g)*u ----------------
__global__ __launch_bounds__(256) void k_sh_inter(
    const float* __restrict__ g, const float* __restrict__ u, float* __restrict__ si)
{
    int i = blockIdx.x * 256 + threadIdx.x;   // 1024*512
    float gv = g[i];
    si[i] = silu(gv) * u[i];
}

// ---------------- final: out[t] = shared_part[t] + sum_k dbuf[slot(t,k)] ----
__global__ __launch_bounds__(256) void k_final(
    const float* __restrict__ dbuf, const int* __restrict__ slotof,
    float* __restrict__ out)
{
    int t = blockIdx.x;
    __shared__ int sl[TOPK];
    if (threadIdx.x < TOPK) sl[threadIdx.x] = slotof[t * TOPK + threadIdx.x];
    __syncthreads();
    #pragma unroll
    for (int rep = 0; rep < 2; ++rep) {
        int j = threadIdx.x * 4 + rep * 1024;
        float4 acc = *(float4*)&out[(long)t * Hh + j];   // shared-down value
        #pragma unroll
        for (int k = 0; k < TOPK; ++k) {
            float4 v = *(const float4*)&dbuf[(long)sl[k] * Hh + j];
            acc.x += v.x; acc.y += v.y; acc.z += v.z; acc.w += v.w;
        }
        *(float4*)&out[(long)t * Hh + j] = acc;
    }
}

extern "C" void kernel_launch(void* const* d_in, const int* in_sizes, int n_in,
                              void* d_out, int out_size, void* d_ws, size_t ws_size,
                              hipStream_t stream) {
    const float* h          = (const float*)d_in[0];
    const float* gate_w     = (const float*)d_in[1];
    const float* gu_w       = (const float*)d_in[2];
    const float* dp_w       = (const float*)d_in[3];
    const float* sh_gate_w  = (const float*)d_in[4];
    const float* sh_up_w    = (const float*)d_in[5];
    const float* sh_down_w  = (const float*)d_in[6];
    const float* sh_gate1_w = (const float*)d_in[7];
    float* out = (float*)d_out;

    char* ws = (char*)d_ws;
    size_t off = 0;
    auto alloc = [&](size_t bytes) {
        void* p = ws + off; off += (bytes + 255) & ~(size_t)255; return p;
    };
    int*   topi    = (int*)  alloc(Nn * TOPK * 4);
    float* rw      = (float*)alloc(Nn * TOPK * 4);
    int*   counts  = (int*)  alloc(Ee * 4);
    int*   padoff  = (int*)  alloc((Ee + 1) * 4);
    int*   cursor  = (int*)  alloc(Ee * 4);
    float* shg     = (float*)alloc(Nn * 4);
    int*   rows    = (int*)  alloc(MAXS * 4);
    float* wt      = (float*)alloc(MAXS * 4);
    int*   slotof  = (int*)  alloc(Nn * TOPK * 4);
    float* gu_buf  = (float*)alloc((size_t)MAXS * 1024 * 4);
    float* interb  = (float*)alloc((size_t)MAXS * 512 * 4);
    float* dbuf    = (float*)alloc((size_t)MAXS * Hh * 4);
    float* gbuf    = (float*)alloc((size_t)Nn * SIi * 4);
    float* ubuf    = (float*)alloc((size_t)Nn * SIi * 4);
    float* shint   = (float*)alloc((size_t)Nn * SIi * 4);

    hipMemsetAsync(counts, 0, Ee * 4, stream);
    hipMemsetAsync(rows, 0xFF, MAXS * 4, stream);   // -1 sentinel

    k_gate<<<Nn, 256, 0, stream>>>(h, gate_w, sh_gate1_w, topi, rw, counts, shg);
    k_offsets<<<1, 64, 0, stream>>>(counts, padoff, cursor);
    k_scatter<<<Nn * TOPK / 256, 256, 0, stream>>>(topi, rw, padoff, cursor,
                                                   rows, wt, slotof);

    // routed up/gate: (slots x 1024) = gathered_X @ gu_w[e]^T   N=1024 -> 4 ntiles
    gemm_nt<0><<<dim3(Ee * 4, 16), 256, 0, stream>>>(
        h, Hh, gu_w, (long)1024 * Hh, Hh, gu_buf, 1024,
        counts, 0, padoff, rows, nullptr, Hh, 4);

    k_inter<<<MAXS * 2, 256, 0, stream>>>(gu_buf, rows, wt, interb);

    // shared gate / up: (1024 x 512) = X @ W^T   N=512 -> 2 ntiles
    gemm_nt<2><<<dim3(2, 16), 256, 0, stream>>>(
        h, Hh, sh_gate_w, 0, Hh, gbuf, SIi,
        nullptr, Nn, nullptr, nullptr, nullptr, Hh, 2);
    gemm_nt<2><<<dim3(2, 16), 256, 0, stream>>>(
        h, Hh, sh_up_w, 0, Hh, ubuf, SIi,
        nullptr, Nn, nullptr, nullptr, nullptr, Hh, 2);

    k_sh_inter<<<Nn * SIi / 256, 256, 0, stream>>>(gbuf, ubuf, shint);

    // shared down: out = shg[n] * (sh_inter @ sh_down_w^T)  (plain store, first)
    gemm_nt<3><<<dim3(8, 16), 256, 0, stream>>>(
        shint, SIi, sh_down_w, 0, SIi, out, Hh,
        nullptr, Nn, nullptr, nullptr, shg, SIi, 8);

    // routed down: dbuf[slot] = inter @ dp_w[e]^T   N=2048 -> 8 ntiles
    gemm_nt<1><<<dim3(Ee * 8, 16), 256, 0, stream>>>(
        interb, Ii, dp_w, (long)Hh * Ii, Ii, dbuf, Hh,
        counts, 0, padoff, rows, nullptr, Ii, 8);

    // out[t] += sum of its 8 expert slots
    k_final<<<Nn, 256, 0, stream>>>(dbuf, slotof, out);
}